// Round 6
// baseline (367.675 us; speedup 1.0000x reference)
//
#include <hip/hip_runtime.h>
#include <hip/hip_cooperative_groups.h>
#include <hip/hip_bf16.h>
#include <math.h>

namespace cg = cooperative_groups;

// N = 100000, E = 3.2M, F_in = 128, H = C = 16. int inputs arrive as int32.
//
// out[d] = dinv[d]*(sum_{s->d} u[s] + u[d]) + b,  u = dinv .* (h @ W).
// R3: global f32 atomics ~19.5G txn/s (unusable for 3.2M scattered).
// R6: sort->CSR->register gather. R7: bf16 messages. R8: 2-pass radix bin.
// R9: XCD swizzle. R10: pipelined gathers = 242us. R11/R12 REGRESSED.
// R13: uint2 gather lanes = 234us. R14 REGRESSED. R15 NEUTRAL-NEG.
// R16 WIN (230.9us): 8 nodes/wave, ~49 waves/CU.
// R17 WIN (224.3us): uint4 gather lanes, 2 lanes/edge. Gathers ~35us each.
// R18 WIN small (221.8us): xw1 4-outputs/thread (xw1 was ~10us, near its
//      51MB read floor). Remaining ~140us = binning chain (5 kernels, each
//      <40us, invisible under fill kernels) + launch bubbles.
// R19: fuse hist->colscan->bucketscan->binC->sortcsr into ONE cooperative
//      kernel (256 blocks x 1024 thr, grid.sync between phases). Kills 4
//      launch bubbles, keeps hist_t/base in L2, sort phase gets 1024 thr,
//      and the prep cost finally becomes VISIBLE in top-5 counters.

#define F_IN 128
#define H 16
#define NPB 128            // nodes per bucket
#define MAX_NB 800         // max buckets (N <= 102400)
#define NBLK 256           // prep blocks (edge-range partition)
#define BINT 1024          // prep threads per block
#define SMAX 4864          // max edges per bucket (mean 4096, +12 sigma)
#define PFD 3              // prefetch depth: 16 slots * 3 = 48 edges/node
#define NPW 8              // nodes per wave
#define NPBLK 32           // nodes per block = 4 waves * NPW

typedef __hip_bfloat16 bf16;

__device__ __forceinline__ float bflo(unsigned v) { return __uint_as_float(v << 16); }
__device__ __forceinline__ float bfhi(unsigned v) { return __uint_as_float(v & 0xffff0000u); }

// physical block -> logical block so logically-adjacent blocks (adjacent output
// runs in packed[]) land on the same XCD (XCD = physical % 8 round-robin).
__device__ __forceinline__ int swz(int p) { return (p & 7) * 32 + (p >> 3); }

// ================= fused preprocessing (cooperative) =========================
// phase 1: per-block bucket histogram -> hist_t[bucket*NBLK + block]
// phase 2: per-bucket exclusive scan over blocks (1024 groups of 256)
// phase 3: exclusive scan over bucket totals (block 0)
// phase 4: place edges -> packed = (dst&127)<<17 | src (LDS cursors)
// phase 5: per-bucket LDS counting sort -> sorted[], rowptr[], dinv[]
__global__ void __launch_bounds__(BINT, 1)
prep_kernel(const int* __restrict__ src, const int* __restrict__ dst,
            unsigned* __restrict__ packed, unsigned* __restrict__ sorted,
            int* __restrict__ hist_t, int* __restrict__ btot,
            int* __restrict__ base, int* __restrict__ rowptr,
            float* __restrict__ dinv, int E, int N, int NB) {
    cg::grid_group grid = cg::this_grid();
    __shared__ int h[MAX_NB];              // 3.2 KB: hist, then cursors
    __shared__ int cs[4 * 256];            // 4 KB: 4 column-scan groups
    __shared__ unsigned ssort[SMAX];       // 19.5 KB: sort buf / scan scratch
    __shared__ int cnt[NPB], offs[NPB], cur[NPB];

    int b = swz(blockIdx.x);
    long long e0 = (long long)E * b / NBLK;
    long long e1 = (long long)E * (b + 1) / NBLK;

    // ---- phase 1: histogram over this block's edge range ----
    for (int i = threadIdx.x; i < NB; i += BINT) h[i] = 0;
    __syncthreads();
    for (long long e = e0 + threadIdx.x; e < e1; e += BINT)
        atomicAdd(&h[dst[e] >> 7], 1);
    __syncthreads();
    for (int i = threadIdx.x; i < NB; i += BINT) hist_t[i * NBLK + b] = h[i];

    grid.sync();

    // ---- phase 2: per-bucket scan over blocks; 4 groups of 256/block ----
    {
        int grp = threadIdx.x >> 8;        // 0..3
        int t = threadIdx.x & 255;
        int col = blockIdx.x * 4 + grp;    // 0..1023 covers NB<=800
        int* s = cs + grp * 256;
        int v = 0;
        if (col < NB) v = hist_t[col * NBLK + t];
        s[t] = v;
        __syncthreads();
        for (int off = 1; off < NBLK; off <<= 1) {
            int w = (t >= off) ? s[t - off] : 0;
            __syncthreads();
            s[t] += w;
            __syncthreads();
        }
        if (col < NB) {
            hist_t[col * NBLK + t] = s[t] - v;
            if (t == NBLK - 1) btot[col] = s[t];
        }
    }

    grid.sync();

    // ---- phase 3: exclusive scan over bucket totals (block 0 only) ----
    if (blockIdx.x == 0) {
        int t = threadIdx.x;
        int* s = (int*)ssort;              // 1024 ints scratch
        s[t] = (t < NB) ? btot[t] : 0;
        __syncthreads();
        for (int off = 1; off < 1024; off <<= 1) {
            int v = (t >= off) ? s[t - off] : 0;
            __syncthreads();
            s[t] += v;
            __syncthreads();
        }
        if (t < NB) base[t] = s[t] - btot[t];
        if (t == NB - 1) base[NB] = s[t];
    }

    grid.sync();

    // ---- phase 4: place edges (cursors in LDS) ----
    for (int i = threadIdx.x; i < NB; i += BINT)
        h[i] = base[i] + hist_t[i * NBLK + b];
    __syncthreads();
    for (long long e = e0 + threadIdx.x; e < e1; e += BINT) {
        int d = dst[e];
        int bk = d >> 7;
        int p = atomicAdd(&h[bk], 1);
        packed[p] = (unsigned)src[e] | ((unsigned)(d & 127) << 17);
    }

    grid.sync();

    // ---- phase 5: per-bucket counting sort -> sorted/rowptr/dinv ----
    for (int bk = blockIdx.x; bk < NB; bk += gridDim.x) {
        int be0 = base[bk];
        int len = base[bk + 1] - be0;
        if (len > SMAX) len = SMAX;
        __syncthreads();
        for (int i = threadIdx.x; i < NPB; i += BINT) cnt[i] = 0;
        __syncthreads();
        for (int i = threadIdx.x; i < len; i += BINT)
            atomicAdd(&cnt[packed[be0 + i] >> 17], 1);
        __syncthreads();
        if (threadIdx.x < NPB) offs[threadIdx.x] = cnt[threadIdx.x];
        __syncthreads();
        for (int off = 1; off < NPB; off <<= 1) {
            int v = 0;
            if (threadIdx.x < NPB && threadIdx.x >= off) v = offs[threadIdx.x - off];
            __syncthreads();
            if (threadIdx.x < NPB) offs[threadIdx.x] += v;
            __syncthreads();
        }
        if (threadIdx.x < NPB) {
            int ex = offs[threadIdx.x] - cnt[threadIdx.x];
            cur[threadIdx.x] = ex;
            int node = bk * NPB + threadIdx.x;
            if (node < N) {
                rowptr[node] = be0 + ex;
                dinv[node] = rsqrtf(1.0f + (float)cnt[threadIdx.x]);
            }
        }
        __syncthreads();
        for (int i = threadIdx.x; i < len; i += BINT) {
            unsigned p = packed[be0 + i];
            int pos = atomicAdd(&cur[p >> 17], 1);
            ssort[pos] = p;
        }
        __syncthreads();
        for (int i = threadIdx.x; i < len; i += BINT) sorted[be0 + i] = ssort[i];
    }
    if (blockIdx.x == 0 && threadIdx.x == 0) rowptr[N] = E;
}

// ---- u[i][j] = dinv[i] * sum_k x[i][k]*W1[k][j]  (bf16 out) ----
// R18: 4 outputs per thread. lane = (row r: tid>>2) x (jq: tid&3 -> 4 ch).
#define XR 64
#define XPAD 132
__global__ void xw1_kernel(const float* __restrict__ x, const float* __restrict__ W1,
                           const float* __restrict__ dinv, bf16* __restrict__ u, int n) {
    __shared__ float sW1[F_IN * H];        // 8 KB, [k*16 + j]
    __shared__ float sx[XR * XPAD];        // 33.8 KB
    for (int t = threadIdx.x; t < F_IN * H; t += 256) sW1[t] = W1[t];

    int basei = blockIdx.x * XR;
    for (int idx = threadIdx.x; idx < XR * 32; idx += 256) {
        int r = idx >> 5;                  // 0..63
        int kk = (idx & 31) << 2;          // 0,4,...,124
        int row = basei + r;
        float4 v = make_float4(0.f, 0.f, 0.f, 0.f);
        if (row < n) v = *(const float4*)(x + (size_t)row * F_IN + kk);
        *(float4*)(sx + r * XPAD + kk) = v;
    }
    __syncthreads();

    int r = threadIdx.x >> 2;              // 0..63
    int jq = (threadIdx.x & 3) << 2;       // 0,4,8,12
    int row = basei + r;
    if (row >= n) return;

    const float* xr = sx + r * XPAD;
    float a0 = 0.f, a1 = 0.f, a2 = 0.f, a3 = 0.f;
#pragma unroll 16
    for (int k = 0; k < F_IN; k++) {
        float xk = xr[k];
        float4 w = *(const float4*)(sW1 + k * H + jq);
        a0 += xk * w.x; a1 += xk * w.y; a2 += xk * w.z; a3 += xk * w.w;
    }
    float di = dinv[row];
    bf16 b0 = __float2bfloat16(di * a0);
    bf16 b1 = __float2bfloat16(di * a1);
    bf16 b2 = __float2bfloat16(di * a2);
    bf16 b3 = __float2bfloat16(di * a3);
    ushort4 pk = make_ushort4(*(unsigned short*)&b0, *(unsigned short*)&b1,
                              *(unsigned short*)&b2, *(unsigned short*)&b3);
    *(ushort4*)((unsigned short*)u + (size_t)row * H + jq) = pk;
}

// ================= pipelined gather core (shared by both layers) =============
// R17 lane layout: b0 = j8 (channel octet: 8 bf16 = uint4 = 16B),
// b1 = p (node parity: 2 nodes per wave-iteration), b2..b5 = g (slot 0..15).
// Depth-2 pipeline (R13 shape): prefetch sorted for pair t+1 while consuming
// uv for pair t; uv for t+1 issued after the consume.
#define GATHER_TILE(UVPTR)                                                      \
    int lane = threadIdx.x & 63;                                                \
    int wave = threadIdx.x >> 6;                                                \
    int j8 = lane & 1, pp = (lane >> 1) & 1, g = lane >> 2;                     \
    int nodeBase = blockIdx.x * NPBLK + wave * NPW;                             \
    int r0c = 0, r1c = 0;                                                       \
    unsigned svc[PFD]; uint4 uvc[PFD];                                          \
    {   int node = nodeBase + pp;                                               \
        if (node < N) { r0c = rowptr[node]; r1c = rowptr[node + 1]; }           \
        _Pragma("unroll")                                                       \
        for (int m = 0; m < PFD; m++) {                                         \
            int k = r0c + g + 16 * m;                                           \
            if (k < r1c) svc[m] = sorted[k];                                    \
        }                                                                       \
        _Pragma("unroll")                                                       \
        for (int m = 0; m < PFD; m++) {                                         \
            int k = r0c + g + 16 * m;                                           \
            if (k < r1c) uvc[m] = UVPTR[(size_t)(svc[m] & 0x1FFFF) * 2 + j8];   \
        }                                                                       \
    }                                                                           \
    for (int t = 0; t < NPW / 2; t++) {                                         \
        int r0n = 0, r1n = 0;                                                   \
        unsigned svn[PFD];                                                      \
        if (t < NPW / 2 - 1) {                                                  \
            int nn = nodeBase + 2 * (t + 1) + pp;                               \
            if (nn < N) { r0n = rowptr[nn]; r1n = rowptr[nn + 1]; }             \
            _Pragma("unroll")                                                   \
            for (int m = 0; m < PFD; m++) {                                     \
                int k = r0n + g + 16 * m;                                       \
                if (k < r1n) svn[m] = sorted[k];                                \
            }                                                                   \
        }                                                                       \
        float a0=0.f,a1=0.f,a2=0.f,a3=0.f,a4=0.f,a5=0.f,a6=0.f,a7=0.f;          \
        _Pragma("unroll")                                                       \
        for (int m = 0; m < PFD; m++) {                                         \
            int k = r0c + g + 16 * m;                                           \
            if (k < r1c) {                                                      \
                a0 += bflo(uvc[m].x); a1 += bfhi(uvc[m].x);                     \
                a2 += bflo(uvc[m].y); a3 += bfhi(uvc[m].y);                     \
                a4 += bflo(uvc[m].z); a5 += bfhi(uvc[m].z);                     \
                a6 += bflo(uvc[m].w); a7 += bfhi(uvc[m].w);                     \
            }                                                                   \
        }                                                                       \
        for (int k = r0c + g + 16 * PFD; k < r1c; k += 16) {                    \
            uint4 va = UVPTR[(size_t)(sorted[k] & 0x1FFFF) * 2 + j8];           \
            a0 += bflo(va.x); a1 += bfhi(va.x);                                 \
            a2 += bflo(va.y); a3 += bfhi(va.y);                                 \
            a4 += bflo(va.z); a5 += bfhi(va.z);                                 \
            a6 += bflo(va.w); a7 += bfhi(va.w);                                 \
        }                                                                       \
        _Pragma("unroll")                                                       \
        for (int off = 4; off <= 32; off <<= 1) {                               \
            a0 += __shfl_xor(a0, off); a1 += __shfl_xor(a1, off);               \
            a2 += __shfl_xor(a2, off); a3 += __shfl_xor(a3, off);               \
            a4 += __shfl_xor(a4, off); a5 += __shfl_xor(a5, off);               \
            a6 += __shfl_xor(a6, off); a7 += __shfl_xor(a7, off);               \
        }                                                                       \
        if (g == 0) {                                                           \
            float* tp = &tile[(wave * NPW + 2 * t + pp) * 16 + 8 * j8];         \
            tp[0]=a0; tp[1]=a1; tp[2]=a2; tp[3]=a3;                             \
            tp[4]=a4; tp[5]=a5; tp[6]=a6; tp[7]=a7;                             \
        }                                                                       \
        if (t < NPW / 2 - 1) {                                                  \
            r0c = r0n; r1c = r1n;                                               \
            _Pragma("unroll")                                                   \
            for (int m = 0; m < PFD; m++) {                                     \
                int k = r0n + g + 16 * m;                                       \
                svc[m] = svn[m];                                                \
                if (k < r1n) uvc[m] = UVPTR[(size_t)(svn[m] & 0x1FFFF) * 2 + j8]; \
            }                                                                   \
        }                                                                       \
    }

// ---- layer-1 gather + finalize ----
__global__ void gatherfin1_kernel(const unsigned* __restrict__ sorted, const int* __restrict__ rowptr,
                                  const bf16* __restrict__ u, const float* __restrict__ dinv,
                                  const float* __restrict__ b1, const float* __restrict__ W2,
                                  bf16* __restrict__ u2, int N) {
    __shared__ float tile[NPBLK * 16];
    __shared__ float sW2[256];
    __shared__ float sb1[16];
    sW2[threadIdx.x] = W2[threadIdx.x];
    if (threadIdx.x < 16) sb1[threadIdx.x] = b1[threadIdx.x];

    const uint4* uvp = (const uint4*)u;   // [node*2 + j8] channel octets
    GATHER_TILE(uvp)
    __syncthreads();

    int jj = threadIdx.x & 15;
    for (int rr = 0; rr < NPBLK / 16; rr++) {
        int rl = (threadIdx.x >> 4) + rr * 16;
        int node = blockIdx.x * NPBLK + rl;
        float h = 0.f, di = 0.f;
        if (node < N) {
            di = dinv[node];
            h = di * (tile[rl * 16 + jj] + __bfloat162float(u[(size_t)node * H + jj])) + sb1[jj];
            h = fmaxf(h, 0.f);
        }
        float acc2 = 0.f;
#pragma unroll
        for (int kk = 0; kk < 16; kk++) {
            float hk = __shfl(h, kk, 16);
            acc2 += hk * sW2[kk * 16 + jj];
        }
        if (node < N) u2[(size_t)node * H + jj] = __float2bfloat16(di * acc2);
    }
}

// ---- layer-2 gather + finalize: log_softmax -> out (f32) ----
__global__ void gatherfin2_kernel(const unsigned* __restrict__ sorted, const int* __restrict__ rowptr,
                                  const bf16* __restrict__ u2, const float* __restrict__ dinv,
                                  const float* __restrict__ b2, float* __restrict__ out, int N) {
    __shared__ float tile[NPBLK * 16];
    __shared__ float sb2[16];
    if (threadIdx.x < 16) sb2[threadIdx.x] = b2[threadIdx.x];

    const uint4* uvp = (const uint4*)u2;
    GATHER_TILE(uvp)
    __syncthreads();

    int jj = threadIdx.x & 15;
    for (int rr = 0; rr < NPBLK / 16; rr++) {
        int rl = (threadIdx.x >> 4) + rr * 16;
        int node = blockIdx.x * NPBLK + rl;
        if (node >= N) continue;
        float di = dinv[node];
        float v = di * (tile[rl * 16 + jj] + __bfloat162float(u2[(size_t)node * H + jj])) + sb2[jj];

        float m = v;
#pragma unroll
        for (int off = 8; off >= 1; off >>= 1) m = fmaxf(m, __shfl_xor(m, off, 16));
        float ex = __expf(v - m);
        float s = ex;
#pragma unroll
        for (int off = 8; off >= 1; off >>= 1) s += __shfl_xor(s, off, 16);

        out[(size_t)node * H + jj] = v - m - __logf(s);
    }
}

extern "C" void kernel_launch(void* const* d_in, const int* in_sizes, int n_in,
                              void* d_out, int out_size, void* d_ws, size_t ws_size,
                              hipStream_t stream) {
    const float* x = (const float*)d_in[0];
    const int* edge_index = (const int*)d_in[1];
    const float* W1 = (const float*)d_in[2];
    const float* b1 = (const float*)d_in[3];
    const float* W2 = (const float*)d_in[4];
    const float* b2 = (const float*)d_in[5];
    float* out = (float*)d_out;

    const int N = in_sizes[0] / F_IN;        // 100000
    const int E = in_sizes[1] / 2;           // 3200000
    const int* src = edge_index;
    const int* dst = edge_index + E;
    const int NB = (N + NPB - 1) / NPB;      // 782

    // ws (4B units): dinv[N] | u[8N] | u2[8N] | packed[E] | sorted[E] |
    //                hist_t[MAX_NB*NBLK] | rowptr[N+1] | btot[NB] | base[NB+1]
    float* dinv = (float*)d_ws;
    bf16* u = (bf16*)(dinv + N);
    bf16* u2 = (bf16*)((unsigned*)u + (size_t)N * H / 2);
    unsigned* packed = (unsigned*)((unsigned*)u2 + (size_t)N * H / 2);
    unsigned* sorted = packed + E;
    int* hist_t = (int*)(sorted + E);
    int* rowptr = hist_t + (size_t)MAX_NB * NBLK;
    int* btot = rowptr + N + 1;
    int* base = btot + NB;

    {
        int E_ = E, N_ = N, NB_ = NB;
        void* args[] = {(void*)&src, (void*)&dst, (void*)&packed, (void*)&sorted,
                        (void*)&hist_t, (void*)&btot, (void*)&base, (void*)&rowptr,
                        (void*)&dinv, (void*)&E_, (void*)&N_, (void*)&NB_};
        hipLaunchCooperativeKernel((void*)prep_kernel, dim3(NBLK), dim3(BINT),
                                   args, 0, stream);
    }

    xw1_kernel<<<(N + XR - 1) / XR, 256, 0, stream>>>(x, W1, dinv, u, N);
    gatherfin1_kernel<<<(N + NPBLK - 1) / NPBLK, 256, 0, stream>>>(sorted, rowptr, u, dinv, b1, W2, u2, N);
    gatherfin2_kernel<<<(N + NPBLK - 1) / NPBLK, 256, 0, stream>>>(sorted, rowptr, u2, dinv, b2, out, N);
}